// Round 1
// baseline (4967.547 us; speedup 1.0000x reference)
//
#include <hip/hip_runtime.h>
#include <hip/hip_bf16.h>
#include <math.h>

#define D 512
#define BB 4
#define TT 4096
#define QB 16
#define KT 16
#define PADROW 516  // 512 + 4 floats pad: breaks 512-stride bank aliasing, keeps 16B align

// ---------------- QKV projection: q,k,v[row][e] = sum_d x[row][d] * W[e][d] ----------------
__global__ __launch_bounds__(256) void qkv_proj(
    const float* __restrict__ x, const float* __restrict__ Wq,
    const float* __restrict__ Wk, const float* __restrict__ Wv,
    float* __restrict__ q, float* __restrict__ k, float* __restrict__ v)
{
    __shared__ __align__(16) float x_s[8][D];
    const int tid = threadIdx.x;
    const long rowbase = (long)blockIdx.x * 8;

    #pragma unroll
    for (int it = 0; it < 4; ++it) {
        int flat = it * 1024 + tid * 4;
        int r = flat >> 9, c = flat & 511;
        *reinterpret_cast<float4*>(&x_s[r][c]) =
            *reinterpret_cast<const float4*>(x + (rowbase + r) * D + c);
    }
    __syncthreads();

    const int e0 = tid, e1 = tid + 256;
    float aq0[8], aq1[8], ak0[8], ak1[8], av0[8], av1[8];
    #pragma unroll
    for (int r = 0; r < 8; ++r) { aq0[r]=0.f; aq1[r]=0.f; ak0[r]=0.f; ak1[r]=0.f; av0[r]=0.f; av1[r]=0.f; }

    const float4* wq0p = reinterpret_cast<const float4*>(Wq + (size_t)e0 * D);
    const float4* wq1p = reinterpret_cast<const float4*>(Wq + (size_t)e1 * D);
    const float4* wk0p = reinterpret_cast<const float4*>(Wk + (size_t)e0 * D);
    const float4* wk1p = reinterpret_cast<const float4*>(Wk + (size_t)e1 * D);
    const float4* wv0p = reinterpret_cast<const float4*>(Wv + (size_t)e0 * D);
    const float4* wv1p = reinterpret_cast<const float4*>(Wv + (size_t)e1 * D);

    for (int dq = 0; dq < 128; ++dq) {
        float4 wq0 = wq0p[dq], wq1 = wq1p[dq];
        float4 wk0 = wk0p[dq], wk1 = wk1p[dq];
        float4 wv0 = wv0p[dq], wv1 = wv1p[dq];
        #pragma unroll
        for (int r = 0; r < 8; ++r) {
            float4 xv = *reinterpret_cast<const float4*>(&x_s[r][dq * 4]);
            aq0[r] += xv.x*wq0.x + xv.y*wq0.y + xv.z*wq0.z + xv.w*wq0.w;
            aq1[r] += xv.x*wq1.x + xv.y*wq1.y + xv.z*wq1.z + xv.w*wq1.w;
            ak0[r] += xv.x*wk0.x + xv.y*wk0.y + xv.z*wk0.z + xv.w*wk0.w;
            ak1[r] += xv.x*wk1.x + xv.y*wk1.y + xv.z*wk1.z + xv.w*wk1.w;
            av0[r] += xv.x*wv0.x + xv.y*wv0.y + xv.z*wv0.z + xv.w*wv0.w;
            av1[r] += xv.x*wv1.x + xv.y*wv1.y + xv.z*wv1.z + xv.w*wv1.w;
        }
    }
    #pragma unroll
    for (int r = 0; r < 8; ++r) {
        size_t o = (size_t)(rowbase + r) * D;
        q[o + e0] = aq0[r]; q[o + e1] = aq1[r];
        k[o + e0] = ak0[r]; k[o + e1] = ak1[r];
        v[o + e0] = av0[r]; v[o + e1] = av1[r];
    }
}

// ---------------- Flash attention (causal, online softmax), fp32 ----------------
// block: 256 threads handles QB=16 query rows of one batch; tiles of KT=16 keys.
__global__ __launch_bounds__(256) void flash_attn(
    const float* __restrict__ q, const float* __restrict__ k,
    const float* __restrict__ v, float* __restrict__ out)
{
    __shared__ __align__(16) float q_s[QB][PADROW];
    __shared__ __align__(16) float k_s[KT][PADROW];
    __shared__ __align__(16) float s_s[QB * KT];
    __shared__ __align__(16) float p_s[QB][KT];
    __shared__ float corr_s[QB];
    __shared__ float l_s[QB];

    const int tid = threadIdx.x;
    const int b = blockIdx.y;
    const long qbase = (long)blockIdx.x * QB;
    const size_t batch_off = (size_t)b * TT * D;

    // stage Q rows
    #pragma unroll
    for (int it = 0; it < 8; ++it) {
        int flat = it * 1024 + tid * 4;
        int r = flat >> 9, c = flat & 511;
        *reinterpret_cast<float4*>(&q_s[r][c]) =
            *reinterpret_cast<const float4*>(q + batch_off + (size_t)(qbase + r) * D + c);
    }

    const int rr = tid >> 4;   // score row  (0..15)
    const int jj = tid & 15;   // score key  (0..15)
    const int d0 = tid, d1 = tid + 256;

    float acc0[QB], acc1[QB];
    #pragma unroll
    for (int r = 0; r < QB; ++r) { acc0[r] = 0.f; acc1[r] = 0.f; }
    float m_r = -INFINITY, l_r = 0.f;   // meaningful for tid < QB only

    const int ntiles = blockIdx.x + 1;
    const float scale = 0.044194173824159216f;  // 1/sqrt(512)

    for (int t = 0; t < ntiles; ++t) {
        const int ks = t * KT;
        __syncthreads();  // prev tile's p_s/corr_s reads done before restage/rewrite
        // stage K tile
        #pragma unroll
        for (int it = 0; it < 8; ++it) {
            int flat = it * 1024 + tid * 4;
            int r = flat >> 9, c = flat & 511;
            *reinterpret_cast<float4*>(&k_s[r][c]) =
                *reinterpret_cast<const float4*>(k + batch_off + (size_t)(ks + r) * D + c);
        }
        __syncthreads();

        // scores: one thread per (row, key)
        float dot = 0.f;
        const float* qrow = q_s[rr];
        const float* krow = k_s[jj];
        for (int dq = 0; dq < 128; ++dq) {
            float4 a = *reinterpret_cast<const float4*>(qrow + dq * 4);
            float4 bb = *reinterpret_cast<const float4*>(krow + dq * 4);
            dot += a.x*bb.x + a.y*bb.y + a.z*bb.z + a.w*bb.w;
        }
        const long kj = ks + jj;
        const long qi = qbase + rr;
        s_s[tid] = (kj <= qi) ? dot * scale : -INFINITY;
        __syncthreads();

        // online softmax per row (row-owner threads)
        if (tid < QB) {
            float mnew = m_r;
            #pragma unroll
            for (int j = 0; j < KT; ++j) mnew = fmaxf(mnew, s_s[tid * KT + j]);
            float corr = __expf(m_r - mnew);   // m_r=-inf on first tile -> corr=0
            float psum = 0.f;
            #pragma unroll
            for (int j = 0; j < KT; ++j) {
                float p = __expf(s_s[tid * KT + j] - mnew);
                p_s[tid][j] = p;
                psum += p;
            }
            l_r = l_r * corr + psum;
            m_r = mnew;
            corr_s[tid] = corr;
        }
        __syncthreads();

        // PV: thread owns dims d0,d1 for all rows
        float vv0[KT], vv1[KT];
        #pragma unroll
        for (int j = 0; j < KT; ++j) {
            const float* vr = v + batch_off + (size_t)(ks + j) * D;
            vv0[j] = vr[d0];
            vv1[j] = vr[d1];
        }
        #pragma unroll
        for (int r = 0; r < QB; ++r) {
            float c = corr_s[r];
            float a0 = acc0[r] * c, a1 = acc1[r] * c;
            const float4* p4 = reinterpret_cast<const float4*>(p_s[r]);
            #pragma unroll
            for (int jq = 0; jq < 4; ++jq) {
                float4 p = p4[jq];
                a0 += p.x*vv0[jq*4+0] + p.y*vv0[jq*4+1] + p.z*vv0[jq*4+2] + p.w*vv0[jq*4+3];
                a1 += p.x*vv1[jq*4+0] + p.y*vv1[jq*4+1] + p.z*vv1[jq*4+2] + p.w*vv1[jq*4+3];
            }
            acc0[r] = a0; acc1[r] = a1;
        }
    }

    if (tid < QB) l_s[tid] = l_r;
    __syncthreads();
    #pragma unroll
    for (int r = 0; r < QB; ++r) {
        float inv = 1.f / l_s[r];
        size_t o = batch_off + (size_t)(qbase + r) * D;
        out[o + d0] = acc0[r] * inv;
        out[o + d1] = acc1[r] * inv;
    }
}

// ---------------- Out projection, in place on d_out (row-local) ----------------
__global__ __launch_bounds__(256) void out_proj(
    const float* __restrict__ Wo, float* __restrict__ io)
{
    __shared__ __align__(16) float c_s[8][D];
    const int tid = threadIdx.x;
    const long rowbase = (long)blockIdx.x * 8;

    #pragma unroll
    for (int it = 0; it < 4; ++it) {
        int flat = it * 1024 + tid * 4;
        int r = flat >> 9, c = flat & 511;
        *reinterpret_cast<float4*>(&c_s[r][c]) =
            *reinterpret_cast<const float4*>(io + (rowbase + r) * D + c);
    }
    __syncthreads();

    const int e0 = tid, e1 = tid + 256;
    float a0[8], a1[8];
    #pragma unroll
    for (int r = 0; r < 8; ++r) { a0[r] = 0.f; a1[r] = 0.f; }
    const float4* w0p = reinterpret_cast<const float4*>(Wo + (size_t)e0 * D);
    const float4* w1p = reinterpret_cast<const float4*>(Wo + (size_t)e1 * D);

    for (int dq = 0; dq < 128; ++dq) {
        float4 w0 = w0p[dq], w1 = w1p[dq];
        #pragma unroll
        for (int r = 0; r < 8; ++r) {
            float4 xv = *reinterpret_cast<const float4*>(&c_s[r][dq * 4]);
            a0[r] += xv.x*w0.x + xv.y*w0.y + xv.z*w0.z + xv.w*w0.w;
            a1[r] += xv.x*w1.x + xv.y*w1.y + xv.z*w1.z + xv.w*w1.w;
        }
    }
    #pragma unroll
    for (int r = 0; r < 8; ++r) {
        size_t o = (size_t)(rowbase + r) * D;
        io[o + e0] = a0[r];
        io[o + e1] = a1[r];
    }
}

extern "C" void kernel_launch(void* const* d_in, const int* in_sizes, int n_in,
                              void* d_out, int out_size, void* d_ws, size_t ws_size,
                              hipStream_t stream) {
    const float* x  = (const float*)d_in[0];
    const float* Wq = (const float*)d_in[1];
    const float* Wk = (const float*)d_in[2];
    const float* Wv = (const float*)d_in[3];
    const float* Wo = (const float*)d_in[4];
    float* out = (float*)d_out;

    const size_t n = (size_t)BB * TT * D;   // 8.4M elements
    float* q = (float*)d_ws;
    float* kk = q + n;
    float* vv = kk + n;

    qkv_proj<<<BB * TT / 8, 256, 0, stream>>>(x, Wq, Wk, Wv, q, kk, vv);
    flash_attn<<<dim3(TT / QB, BB), 256, 0, stream>>>(q, kk, vv, out);
    out_proj<<<BB * TT / 8, 256, 0, stream>>>(Wo, out);
}

// Round 3
// 687.876 us; speedup vs baseline: 7.2216x; 7.2216x over previous
//
#include <hip/hip_runtime.h>
#include <hip/hip_bf16.h>
#include <math.h>

#define D 512
#define BB 4
#define TT 4096

typedef __attribute__((ext_vector_type(8))) short short8v;
typedef __attribute__((ext_vector_type(4))) short short4v;
typedef __attribute__((ext_vector_type(4))) float float4v;

__device__ inline short f2bf(float x) {
    __hip_bfloat16 h = __float2bfloat16(x);
    return *reinterpret_cast<short*>(&h);
}

// ============ QKV projection: C[t][e] = alpha * sum_d x[t][d] * W[e][d], bf16 out ============
// learn_hip m33/m90-class single-buffer barrier pattern (replay-proven structure).
__global__ __launch_bounds__(256) void gemm_qkv(
    const float* __restrict__ x,
    const float* __restrict__ Wq, const float* __restrict__ Wk, const float* __restrict__ Wv,
    __hip_bfloat16* __restrict__ q, __hip_bfloat16* __restrict__ k, __hip_bfloat16* __restrict__ v)
{
    const float* W; __hip_bfloat16* C; float alpha;
    if (blockIdx.z == 0)      { W = Wq; C = q; alpha = 0.044194173824159216f; } // fold 1/sqrt(512)
    else if (blockIdx.z == 1) { W = Wk; C = k; alpha = 1.f; }
    else                      { W = Wv; C = v; alpha = 1.f; }

    __shared__ short As[64][72];   // +8 bf16 pad -> conflict-floor b128 reads
    __shared__ short Bs[64][72];
    const int tid = threadIdx.x;
    const int m0 = blockIdx.x * 64, n0 = blockIdx.y * 64;
    const int w = tid >> 6, lane = tid & 63, lm = lane & 15, g = lane >> 4;

    float4v acc[4];
    #pragma unroll
    for (int i = 0; i < 4; ++i) acc[i] = (float4v){0.f,0.f,0.f,0.f};

    for (int k0 = 0; k0 < 512; k0 += 64) {
        __syncthreads();
        #pragma unroll
        for (int u = 0; u < 4; ++u) {          // stage A (x), convert f32->bf16
            int ch = tid + 256*u;
            int r = ch >> 4, c = (ch & 15) * 4;
            float4 xv = *reinterpret_cast<const float4*>(x + (size_t)(m0 + r)*512 + k0 + c);
            short4v sv = { f2bf(xv.x), f2bf(xv.y), f2bf(xv.z), f2bf(xv.w) };
            *reinterpret_cast<short4v*>(&As[r][c]) = sv;
        }
        #pragma unroll
        for (int u = 0; u < 4; ++u) {          // stage B (W rows)
            int ch = tid + 256*u;
            int r = ch >> 4, c = (ch & 15) * 4;
            float4 wv = *reinterpret_cast<const float4*>(W + (size_t)(n0 + r)*512 + k0 + c);
            short4v sv = { f2bf(wv.x), f2bf(wv.y), f2bf(wv.z), f2bf(wv.w) };
            *reinterpret_cast<short4v*>(&Bs[r][c]) = sv;
        }
        __syncthreads();
        #pragma unroll
        for (int ks = 0; ks < 2; ++ks) {
            short8v a = *reinterpret_cast<const short8v*>(&As[16*w + lm][ks*32 + 8*g]);
            #pragma unroll
            for (int nt = 0; nt < 4; ++nt) {
                short8v bv = *reinterpret_cast<const short8v*>(&Bs[16*nt + lm][ks*32 + 8*g]);
                acc[nt] = __builtin_amdgcn_mfma_f32_16x16x32_bf16(a, bv, acc[nt], 0, 0, 0);
            }
        }
    }
    #pragma unroll
    for (int nt = 0; nt < 4; ++nt)
        #pragma unroll
        for (int r = 0; r < 4; ++r) {
            int row = m0 + 16*w + 4*g + r;     // D: row = 4*(lane>>4)+reg, col = lane&15
            int col = n0 + 16*nt + lm;
            C[(size_t)row*512 + col] = __float2bfloat16(acc[nt][r] * alpha);
        }
}

// ============ V transpose with sigma-permuted columns ============
// vt[b][d][32-block of t, order pos(tau)] so a PV B-fragment is ONE contiguous 16B load.
// pos(tau) = 8*((tau&15)>>2) + (tau&3) + 4*(tau>>4): lane g reads pos 8g..8g+7 =
// keys {4g..4g+3, 16+4g..16+4g+3} — exactly the MFMA sigma the P-fragment carries.
__global__ __launch_bounds__(256) void transpose_v(
    const __hip_bfloat16* __restrict__ vin, __hip_bfloat16* __restrict__ vout)
{
    const int tid = threadIdx.x;
    const int b = blockIdx.y;
    const int t = blockIdx.x * 32 + (tid & 31);
    const int tau = t & 31;
    const int tp = (t & ~31) + 8*((tau & 15) >> 2) + (tau & 3) + 4*(tau >> 4);
    const short* src = (const short*)vin + (size_t)(b*TT + t)*D;
    short* dst = (short*)vout + (size_t)b*D*TT;
    #pragma unroll
    for (int u = 0; u < 8; ++u) {
        int cf = (tid >> 5) + 8*u;             // 0..63 (16B chunk within row)
        short8v vv = *reinterpret_cast<const short8v*>(src + cf*8);
        #pragma unroll
        for (int i = 0; i < 8; ++i)
            dst[(size_t)(cf*8 + i)*TT + tp] = vv[i];
    }
}

// ============ Flash attention: single wave per block, ZERO LDS, ZERO barriers ============
// Provably race-free: wave-synchronous, no shared state. QB=16 q-rows/wave, KT=64 keys/tile.
// K read direct from global (each tile byte read exactly once per wave, 16 rows x 64B coalesced).
__global__ __launch_bounds__(64, 1) void attn(
    const __hip_bfloat16* __restrict__ qg, const __hip_bfloat16* __restrict__ kg,
    const __hip_bfloat16* __restrict__ vtg, __hip_bfloat16* __restrict__ ctx)
{
    const int lane = threadIdx.x;              // 64 threads = 1 wave
    const int lm = lane & 15, g = lane >> 4;
    const int idx = blockIdx.x;
    const int b  = idx & 3;                    // batch -> XCD spread
    const int qb = 255 - (idx >> 2);           // descending work order
    const int qbase = qb * 16;
    const int qrow  = qbase + lm;

    const short* qp = (const short*)qg  + (size_t)b*TT*D;
    const short* kp = (const short*)kg  + (size_t)b*TT*D;
    const short* vp = (const short*)vtg + (size_t)b*D*TT;

    // hoist Q fragments: lane (g,lm) holds Q[qrow][32s+8g .. +8]
    short8v qf[16];
    #pragma unroll
    for (int s = 0; s < 16; ++s)
        qf[s] = *reinterpret_cast<const short8v*>(qp + (size_t)qrow*D + 32*s + 8*g);

    float4v acc[32];
    #pragma unroll
    for (int i = 0; i < 32; ++i) acc[i] = (float4v){0.f,0.f,0.f,0.f};
    float m_r = -INFINITY, l_r = 0.f;

    const int ntiles = (qbase + 16 + 63) >> 6;
    for (int t = 0; t < ntiles; ++t) {
        const int ks0 = t * 64;

        // S^T[kj][q]: 4 subtiles of 16 kj, K=512
        float4v sc[4];
        #pragma unroll
        for (int i = 0; i < 4; ++i) sc[i] = (float4v){0.f,0.f,0.f,0.f};
        #pragma unroll
        for (int s = 0; s < 16; ++s) {
            #pragma unroll
            for (int sub = 0; sub < 4; ++sub) {
                short8v a = *reinterpret_cast<const short8v*>(
                    kp + (size_t)(ks0 + 16*sub + lm)*D + 32*s + 8*g);
                sc[sub] = __builtin_amdgcn_mfma_f32_16x16x32_bf16(a, qf[s], sc[sub], 0, 0, 0);
            }
        }

        // causal mask + online softmax; lane holds kj = ks0 + 16*sub + 4g + r for q = qrow
        float p[16];
        #pragma unroll
        for (int sub = 0; sub < 4; ++sub)
            #pragma unroll
            for (int r = 0; r < 4; ++r) {
                int kj = ks0 + 16*sub + 4*g + r;
                p[4*sub + r] = (kj <= qrow) ? sc[sub][r] : -3.0e38f;
            }
        float mx = p[0];
        #pragma unroll
        for (int i = 1; i < 16; ++i) mx = fmaxf(mx, p[i]);
        mx = fmaxf(mx, __shfl_xor(mx, 16));
        mx = fmaxf(mx, __shfl_xor(mx, 32));
        float mnew = fmaxf(m_r, mx);
        float corr = __expf(m_r - mnew);       // first tile: expf(-inf)=0
        float psum = 0.f;
        #pragma unroll
        for (int i = 0; i < 16; ++i) { p[i] = __expf(p[i] - mnew); psum += p[i]; }
        psum += __shfl_xor(psum, 16);
        psum += __shfl_xor(psum, 32);
        l_r = l_r * corr + psum;
        m_r = mnew;

        float c4[4];
        #pragma unroll
        for (int r = 0; r < 4; ++r) c4[r] = __shfl(corr, 4*g + r);  // corr for acc-row q=4g+r
        #pragma unroll
        for (int dt = 0; dt < 32; ++dt) {
            acc[dt][0] *= c4[0]; acc[dt][1] *= c4[1];
            acc[dt][2] *= c4[2]; acc[dt][3] *= c4[3];
        }

        // P fragments (lane-local, matches V sigma): pf0 = keys [ks0,ks0+32), pf1 = +32
        short8v pf0, pf1;
        #pragma unroll
        for (int i = 0; i < 8; ++i) { pf0[i] = f2bf(p[i]); pf1[i] = f2bf(p[8 + i]); }

        // PV: B-frag = one 16B load from sigma-permuted vt
        #pragma unroll
        for (int dt = 0; dt < 32; ++dt) {
            const short* vrow = vp + (size_t)(16*dt + lm)*TT + ks0 + 8*g;
            short8v v0 = *reinterpret_cast<const short8v*>(vrow);
            short8v v1 = *reinterpret_cast<const short8v*>(vrow + 32);
            acc[dt] = __builtin_amdgcn_mfma_f32_16x16x32_bf16(pf0, v0, acc[dt], 0, 0, 0);
            acc[dt] = __builtin_amdgcn_mfma_f32_16x16x32_bf16(pf1, v1, acc[dt], 0, 0, 0);
        }
    }

    float inv = 1.f / l_r;
    float i4[4];
    #pragma unroll
    for (int r = 0; r < 4; ++r) i4[r] = __shfl(inv, 4*g + r);
    __hip_bfloat16* cp = ctx + (size_t)b*TT*D;
    #pragma unroll
    for (int dt = 0; dt < 32; ++dt)
        #pragma unroll
        for (int r = 0; r < 4; ++r) {
            int row = qbase + 4*g + r;
            cp[(size_t)row*D + 16*dt + lm] = __float2bfloat16(acc[dt][r] * i4[r]);
        }
}

// ============ Output projection: d_out[t][e] = sum_d ctx[t][d] * Wo[e][d], f32 out ============
__global__ __launch_bounds__(256) void gemm_out(
    const __hip_bfloat16* __restrict__ Ab, const float* __restrict__ W,
    float* __restrict__ Cf)
{
    __shared__ short As[64][72];
    __shared__ short Bs[64][72];
    const int tid = threadIdx.x;
    const int m0 = blockIdx.x * 64, n0 = blockIdx.y * 64;
    const int w = tid >> 6, lane = tid & 63, lm = lane & 15, g = lane >> 4;
    const short* Ap = (const short*)Ab;

    float4v acc[4];
    #pragma unroll
    for (int i = 0; i < 4; ++i) acc[i] = (float4v){0.f,0.f,0.f,0.f};

    for (int k0 = 0; k0 < 512; k0 += 64) {
        __syncthreads();
        #pragma unroll
        for (int u = 0; u < 2; ++u) {          // stage A (bf16 ctx)
            int ch = tid + 256*u;
            int r = ch >> 3, c = (ch & 7) * 8;
            *reinterpret_cast<short8v*>(&As[r][c]) =
                *reinterpret_cast<const short8v*>(Ap + (size_t)(m0 + r)*512 + k0 + c);
        }
        #pragma unroll
        for (int u = 0; u < 4; ++u) {          // stage B (Wo f32 -> bf16)
            int ch = tid + 256*u;
            int r = ch >> 4, c = (ch & 15) * 4;
            float4 wv = *reinterpret_cast<const float4*>(W + (size_t)(n0 + r)*512 + k0 + c);
            short4v sv = { f2bf(wv.x), f2bf(wv.y), f2bf(wv.z), f2bf(wv.w) };
            *reinterpret_cast<short4v*>(&Bs[r][c]) = sv;
        }
        __syncthreads();
        #pragma unroll
        for (int ks = 0; ks < 2; ++ks) {
            short8v a = *reinterpret_cast<const short8v*>(&As[16*w + lm][ks*32 + 8*g]);
            #pragma unroll
            for (int nt = 0; nt < 4; ++nt) {
                short8v bv = *reinterpret_cast<const short8v*>(&Bs[16*nt + lm][ks*32 + 8*g]);
                acc[nt] = __builtin_amdgcn_mfma_f32_16x16x32_bf16(a, bv, acc[nt], 0, 0, 0);
            }
        }
    }
    #pragma unroll
    for (int nt = 0; nt < 4; ++nt)
        #pragma unroll
        for (int r = 0; r < 4; ++r) {
            int row = m0 + 16*w + 4*g + r;
            int col = n0 + 16*nt + lm;
            Cf[(size_t)row*512 + col] = acc[nt][r];
        }
}

extern "C" void kernel_launch(void* const* d_in, const int* in_sizes, int n_in,
                              void* d_out, int out_size, void* d_ws, size_t ws_size,
                              hipStream_t stream) {
    const float* x  = (const float*)d_in[0];
    const float* Wq = (const float*)d_in[1];
    const float* Wk = (const float*)d_in[2];
    const float* Wv = (const float*)d_in[3];
    const float* Wo = (const float*)d_in[4];
    float* out = (float*)d_out;

    const size_t n = (size_t)BB * TT * D;                 // 8.4M elems
    __hip_bfloat16* qb   = (__hip_bfloat16*)d_ws;
    __hip_bfloat16* kb   = qb + n;
    __hip_bfloat16* vb   = kb + n;
    __hip_bfloat16* vt   = vb + n;
    __hip_bfloat16* ctxb = vt + n;                        // total 5n*2B = 80MB

    gemm_qkv<<<dim3(256, 8, 3), 256, 0, stream>>>(x, Wq, Wk, Wv, qb, kb, vb);
    transpose_v<<<dim3(TT / 32, BB), 256, 0, stream>>>(vb, vt);
    attn<<<dim3(256 * BB), 64, 0, stream>>>(qb, kb, vt, ctxb);
    gemm_out<<<dim3(256, 8, 1), 256, 0, stream>>>(ctxb, Wo, out);
}